// Round 3
// baseline (304.795 us; speedup 1.0000x reference)
//
#include <hip/hip_runtime.h>
#include <math.h>

#define BB 2
#define TT 2048
#define DD 1024
#define NH 16
#define HDD 64

typedef __attribute__((ext_vector_type(8))) short v8s;     // 8 bf16 in 4 VGPRs
typedef __attribute__((ext_vector_type(4))) short v4s;     // 4 bf16 in 2 VGPRs
typedef __attribute__((ext_vector_type(4))) float f32x4;   // MFMA C/D

__device__ __forceinline__ unsigned short f2bf(float f) {
    union { float f; unsigned int u; } c; c.f = f;
    unsigned int r = c.u + 0x7FFF + ((c.u >> 16) & 1);     // RNE
    return (unsigned short)(r >> 16);
}

__device__ __forceinline__ void gload_lds16(const void* g, void* l) {
    __builtin_amdgcn_global_load_lds(
        (const __attribute__((address_space(1))) void*)g,
        (__attribute__((address_space(3))) void*)l, 16, 0, 0);
}

// K=16 bf16 MFMA: prefer the legacy builtin, else raw ISA (v_mfma_f32_16x16x16_bf16
// is in the gfx950 ISA table: A/B = 2 VGPRs (4 bf16), C/D = 4).
__device__ __forceinline__ f32x4 mfma16x16x16bf16(v4s a, v4s b, f32x4 c) {
#if __has_builtin(__builtin_amdgcn_mfma_f32_16x16x16bf16_1k)
    return __builtin_amdgcn_mfma_f32_16x16x16bf16_1k(a, b, c, 0, 0, 0);
#else
    f32x4 d;
    asm volatile("v_mfma_f32_16x16x16_bf16 %0, %1, %2, %3"
                 : "=v"(d) : "v"(a), "v"(b), "v"(c));
    return d;
#endif
}

// ============================================================================
// Cast fp32 -> bf16 for x, Wq, Wk, Wv, Wo (blockIdx.y selects tensor).
// ============================================================================
__global__ __launch_bounds__(256) void cast5_kernel(
    const float* __restrict__ x, const float* __restrict__ wq,
    const float* __restrict__ wk, const float* __restrict__ wv,
    const float* __restrict__ wo,
    unsigned short* __restrict__ xo, unsigned short* __restrict__ wqo,
    unsigned short* __restrict__ wko, unsigned short* __restrict__ wvo,
    unsigned short* __restrict__ woo)
{
    const float* s; unsigned short* d; int n4;
    switch (blockIdx.y) {
        case 0: s = x;  d = xo;  n4 = BB * TT * DD / 4; break;
        case 1: s = wq; d = wqo; n4 = DD * DD / 4; break;
        case 2: s = wk; d = wko; n4 = DD * DD / 4; break;
        case 3: s = wv; d = wvo; n4 = DD * DD / 4; break;
        default: s = wo; d = woo; n4 = DD * DD / 4; break;
    }
    int i = blockIdx.x * 256 + threadIdx.x;
    if (i < n4) {
        float4 v = ((const float4*)s)[i];
        ushort4 o;
        o.x = f2bf(v.x); o.y = f2bf(v.y); o.z = f2bf(v.z); o.w = f2bf(v.w);
        ((ushort4*)d)[i] = o;
    }
}

// ============================================================================
// QKV projection: bf16 MFMA B^T GEMM, 128x128 tile, BK=32, global_load_lds.
// q stored (B,H,T,HD); k stored (B,H,T,HD) PRE-SCALED by 0.125 (exact pow2,
// folds softmax 1/sqrt(HD) into the GEMM epilogue); v stored (B,H,HD,T).
// ============================================================================
__global__ __launch_bounds__(256) void qkv_mfma(
    const unsigned short* __restrict__ x,
    const unsigned short* __restrict__ wq, const unsigned short* __restrict__ wk,
    const unsigned short* __restrict__ wv,
    unsigned short* __restrict__ qo, unsigned short* __restrict__ ko,
    unsigned short* __restrict__ vo)
{
    __shared__ unsigned short As[128 * 32];
    __shared__ unsigned short Bs[128 * 32];

    const int tid = threadIdx.x;
    const int lane = tid & 63;
    const int wid = tid >> 6;
    const int l15 = lane & 15, quad = lane >> 4;

    const int m0 = blockIdx.x << 7;
    const int ny = blockIdx.y;
    const int which = ny >> 3;                // 0=q 1=k 2=v
    const int n0 = (ny & 7) << 7;
    const unsigned short* W = (which == 0) ? wq : (which == 1) ? wk : wv;

    const int wm = (wid >> 1) << 6;
    const int wn = (wid & 1) << 6;

    f32x4 acc[4][4] = {};

    for (int k0 = 0; k0 < DD; k0 += 32) {
        __syncthreads();
#pragma unroll
        for (int u = 0; u < 2; ++u) {
            const int f = (wid << 11) + (u << 10) + (lane << 4);
            const int row = f >> 6;
            const int cs = (f & 63) >> 1;
            gload_lds16(&x[(size_t)(m0 + row) * DD + k0 + cs], ((char*)As) + f);
            gload_lds16(&W[(size_t)(n0 + row) * DD + k0 + cs], ((char*)Bs) + f);
        }
        __syncthreads();

        v8s af[4], bf[4];
#pragma unroll
        for (int i = 0; i < 4; ++i)
            af[i] = *(const v8s*)(((const char*)As) + (wm + (i << 4) + l15) * 64 + (quad << 4));
#pragma unroll
        for (int j = 0; j < 4; ++j)
            bf[j] = *(const v8s*)(((const char*)Bs) + (wn + (j << 4) + l15) * 64 + (quad << 4));
#pragma unroll
        for (int i = 0; i < 4; ++i)
#pragma unroll
            for (int j = 0; j < 4; ++j)
                acc[i][j] = __builtin_amdgcn_mfma_f32_16x16x32_bf16(af[i], bf[j], acc[i][j], 0, 0, 0);
    }

    if (which < 2) {
        unsigned short* outp = (which == 0) ? qo : ko;
        const float sc = (which == 1) ? 0.125f : 1.0f;   // fold 1/sqrt(HD) into K
#pragma unroll
        for (int i = 0; i < 4; ++i)
#pragma unroll
            for (int j = 0; j < 4; ++j) {
                const int n = n0 + wn + (j << 4) + l15;
                const int h = n >> 6, hd = n & 63;
#pragma unroll
                for (int r = 0; r < 4; ++r) {
                    const int m = m0 + wm + (i << 4) + (quad << 2) + r;
                    const int b = m >> 11, t = m & 2047;
                    outp[(((size_t)(b * NH + h) * TT + t) << 6) + hd] = f2bf(acc[i][j][r] * sc);
                }
            }
    } else {
#pragma unroll
        for (int i = 0; i < 4; ++i)
#pragma unroll
            for (int j = 0; j < 4; ++j) {
                const int n = n0 + wn + (j << 4) + l15;
                const int h = n >> 6, hd = n & 63;
                const int mb = m0 + wm + (i << 4) + (quad << 2);
                const int b = mb >> 11, t = mb & 2047;
                ushort4 pk;
                pk.x = f2bf(acc[i][j][0]); pk.y = f2bf(acc[i][j][1]);
                pk.z = f2bf(acc[i][j][2]); pk.w = f2bf(acc[i][j][3]);
                *(ushort4*)&vo[((((size_t)(b * NH + h) << 6) + hd) << 11) + t] = pk;
            }
    }
}

// ============================================================================
// Flash attention, bf16 MFMA, S^T formulation.
// Per wave: St[64k x 16q] = K_tile . Q_wave^T  (4x m-tiles of 16x16x32 MFMA).
// C-layout => lane owns ONE q-row (col=l15): softmax = 15 in-reg ops + 2 shfl.
// P^T C-layout chunks (k=quad*4+r, n=q) == B-frag of K=16 MFMA exactly, so
// PV runs as O^T += Vt . P^T with NO LDS round-trip.
// 1 q-tile/block, longest-first (qt = 31-bx) for load balance; K/V register
// prefetch overlaps global latency with compute.  LDS 27.6 KB.
// ============================================================================
__global__ __launch_bounds__(256) void attn_mfma(
    const unsigned short* __restrict__ q, const unsigned short* __restrict__ k,
    const unsigned short* __restrict__ vt, unsigned short* __restrict__ ctx)
{
    __shared__ unsigned short Qs[64][72];
    __shared__ unsigned short Ks[64][72];
    __shared__ unsigned short Vts[64][72];

    const int tid = threadIdx.x;
    const int lane = tid & 63;
    const int wid = tid >> 6;
    const int l15 = lane & 15, quad = lane >> 4;
    const int bh = blockIdx.y;

    const unsigned short* qb = q + (size_t)bh * TT * HDD;
    const unsigned short* kb = k + (size_t)bh * TT * HDD;
    const unsigned short* vb = vt + (size_t)bh * HDD * TT;   // (HD, T)
    unsigned short* cb = ctx + (size_t)bh * TT * HDD;

    const int cr = tid >> 3;            // staging row 0..31 (x2 rounds)
    const int cc = (tid & 7) << 3;      // staging col (ushort), 16B chunks

    const int qt = 31 - (int)blockIdx.x;   // longest blocks dispatch first
    const int q0 = qt << 6;
    const int qrow = q0 + (wid << 4) + l15;   // this lane's q-row

    // Q tile -> LDS, then wave-resident Q B-frags (B-frag(Q^T) == A-frag(Q))
#pragma unroll
    for (int u = 0; u < 2; ++u) {
        const int r = cr + (u << 5);
        *(uint4*)&Qs[r][cc] = *(const uint4*)&qb[(size_t)(q0 + r) * HDD + cc];
    }
    __syncthreads();
    v8s qf[2];
#pragma unroll
    for (int c = 0; c < 2; ++c)
        qf[c] = *(const v8s*)&Qs[(wid << 4) + l15][(c << 5) + (quad << 3)];

    // prefetch K/V tile jt=0 into registers
    uint4 kpre[2], vpre[2];
#pragma unroll
    for (int u = 0; u < 2; ++u) {
        const int r = cr + (u << 5);
        kpre[u] = *(const uint4*)&kb[(size_t)r * HDD + cc];
        vpre[u] = *(const uint4*)&vb[((size_t)r << 11) + cc];
    }

    float m_i = -INFINITY, l_i = 0.f;
    f32x4 o[4] = {};                    // O^T: d = m*16 + quad*4 + r, col q=l15

    for (int jt = 0; jt <= qt; ++jt) {
        const int k0 = jt << 6;
        __syncthreads();                // prev-tile LDS reads complete
#pragma unroll
        for (int u = 0; u < 2; ++u) {
            const int r = cr + (u << 5);
            *(uint4*)&Ks[r][cc] = kpre[u];
            *(uint4*)&Vts[r][cc] = vpre[u];
        }
        __syncthreads();

        if (jt < qt) {                  // prefetch next tile
            const int kn = k0 + 64;
#pragma unroll
            for (int u = 0; u < 2; ++u) {
                const int r = cr + (u << 5);
                kpre[u] = *(const uint4*)&kb[(size_t)(kn + r) * HDD + cc];
                vpre[u] = *(const uint4*)&vb[((size_t)r << 11) + kn + cc];
            }
        }

        // S^T = K . Q^T : St[k = m*16+quad*4+r][q = l15]  (K pre-scaled by 1/8)
        f32x4 s[4] = {};
#pragma unroll
        for (int m = 0; m < 4; ++m) {
            const v8s kf0 = *(const v8s*)&Ks[(m << 4) + l15][quad << 3];
            const v8s kf1 = *(const v8s*)&Ks[(m << 4) + l15][32 + (quad << 3)];
            s[m] = __builtin_amdgcn_mfma_f32_16x16x32_bf16(kf0, qf[0], s[m], 0, 0, 0);
            s[m] = __builtin_amdgcn_mfma_f32_16x16x32_bf16(kf1, qf[1], s[m], 0, 0, 0);
        }

        if (jt == qt) {                 // causal mask, diagonal tile only
#pragma unroll
            for (int m = 0; m < 4; ++m) {
                const int kc = k0 + (m << 4) + (quad << 2);
#pragma unroll
                for (int r = 0; r < 4; ++r)
                    if (kc + r > qrow) s[m][r] = -INFINITY;
            }
        }

        // online softmax: one q-row per lane; 16 in-reg values + quad lanes
        float mx = fmaxf(fmaxf(s[0][0], s[0][1]), fmaxf(s[0][2], s[0][3]));
        mx = fmaxf(mx, fmaxf(fmaxf(s[1][0], s[1][1]), fmaxf(s[1][2], s[1][3])));
        mx = fmaxf(mx, fmaxf(fmaxf(s[2][0], s[2][1]), fmaxf(s[2][2], s[2][3])));
        mx = fmaxf(mx, fmaxf(fmaxf(s[3][0], s[3][1]), fmaxf(s[3][2], s[3][3])));
        mx = fmaxf(mx, __shfl_xor(mx, 16));
        mx = fmaxf(mx, __shfl_xor(mx, 32));
        const float m_new = fmaxf(m_i, mx);
        const float alpha = __expf(m_i - m_new);
        m_i = m_new;

        float sum = 0.f;
        v4s pf[4];
#pragma unroll
        for (int m = 0; m < 4; ++m) {
            v4s t;
#pragma unroll
            for (int r = 0; r < 4; ++r) {
                const float pv = __expf(s[m][r] - m_new);
                sum += pv;
                t[r] = (short)f2bf(pv);
            }
            pf[m] = t;
        }
        sum += __shfl_xor(sum, 16);
        sum += __shfl_xor(sum, 32);
        l_i = l_i * alpha + sum;

#pragma unroll
        for (int m = 0; m < 4; ++m)
#pragma unroll
            for (int r = 0; r < 4; ++r)
                o[m][r] *= alpha;

        // O^T += Vt . P^T   (A = Vt 16x16 chunk, B = P^T chunk from regs)
#pragma unroll
        for (int m = 0; m < 4; ++m)
#pragma unroll
            for (int c = 0; c < 4; ++c) {
                const v4s vf = *(const v4s*)&Vts[(m << 4) + l15][(c << 4) + (quad << 2)];
                o[m] = mfma16x16x16bf16(vf, pf[c], o[m]);
            }
    }

    // normalize + store: ctx[q][d], d = m*16 + quad*4 + r (8B stores)
    const float linv = 1.f / l_i;
#pragma unroll
    for (int m = 0; m < 4; ++m) {
        ushort4 st;
        st.x = f2bf(o[m][0] * linv); st.y = f2bf(o[m][1] * linv);
        st.z = f2bf(o[m][2] * linv); st.w = f2bf(o[m][3] * linv);
        *(ushort4*)&cb[((size_t)qrow << 6) + (m << 4) + (quad << 2)] = st;
    }
}

// ============================================================================
// Output projection: ctx (bf16, flat 4096x1024 = faithful reshape) x Wo^T + bo
// ============================================================================
__global__ __launch_bounds__(256) void oproj_mfma(
    const unsigned short* __restrict__ c, const unsigned short* __restrict__ wo,
    const float* __restrict__ bo, float* __restrict__ out)
{
    __shared__ unsigned short As[128 * 32];
    __shared__ unsigned short Bs[128 * 32];

    const int tid = threadIdx.x;
    const int lane = tid & 63;
    const int wid = tid >> 6;
    const int l15 = lane & 15, quad = lane >> 4;

    const int m0 = blockIdx.x << 7;
    const int n0 = blockIdx.y << 7;
    const int wm = (wid >> 1) << 6, wn = (wid & 1) << 6;

    f32x4 acc[4][4] = {};

    for (int k0 = 0; k0 < DD; k0 += 32) {
        __syncthreads();
#pragma unroll
        for (int u = 0; u < 2; ++u) {
            const int f = (wid << 11) + (u << 10) + (lane << 4);
            const int row = f >> 6;
            const int cs = (f & 63) >> 1;
            gload_lds16(&c[(size_t)(m0 + row) * DD + k0 + cs], ((char*)As) + f);
            gload_lds16(&wo[(size_t)(n0 + row) * DD + k0 + cs], ((char*)Bs) + f);
        }
        __syncthreads();

        v8s af[4], bf[4];
#pragma unroll
        for (int i = 0; i < 4; ++i)
            af[i] = *(const v8s*)(((const char*)As) + (wm + (i << 4) + l15) * 64 + (quad << 4));
#pragma unroll
        for (int j = 0; j < 4; ++j)
            bf[j] = *(const v8s*)(((const char*)Bs) + (wn + (j << 4) + l15) * 64 + (quad << 4));
#pragma unroll
        for (int i = 0; i < 4; ++i)
#pragma unroll
            for (int j = 0; j < 4; ++j)
                acc[i][j] = __builtin_amdgcn_mfma_f32_16x16x32_bf16(af[i], bf[j], acc[i][j], 0, 0, 0);
    }

#pragma unroll
    for (int j = 0; j < 4; ++j) {
        const int n = n0 + wn + (j << 4) + l15;
        const float bias = bo[n];
#pragma unroll
        for (int i = 0; i < 4; ++i) {
            const int mb = m0 + wm + (i << 4) + (quad << 2);
#pragma unroll
            for (int r = 0; r < 4; ++r)
                out[(size_t)(mb + r) * DD + n] = acc[i][j][r] + bias;
        }
    }
}

extern "C" void kernel_launch(void* const* d_in, const int* in_sizes, int n_in,
                              void* d_out, int out_size, void* d_ws, size_t ws_size,
                              hipStream_t stream) {
    const float* x  = (const float*)d_in[0];
    const float* Wq = (const float*)d_in[1];
    const float* Wk = (const float*)d_in[2];
    const float* Wv = (const float*)d_in[3];
    const float* Wo = (const float*)d_in[4];
    const float* bo = (const float*)d_in[5];
    float* out = (float*)d_out;

    const size_t NX = (size_t)BB * TT * DD;
    const size_t NW = (size_t)DD * DD;

    unsigned short* xb  = (unsigned short*)d_ws;
    unsigned short* wqb = xb + NX;
    unsigned short* wkb = wqb + NW;
    unsigned short* wvb = wkb + NW;
    unsigned short* wob = wvb + NW;
    unsigned short* qb  = wob + NW;
    unsigned short* kb  = qb + NX;
    unsigned short* vtb = kb + NX;
    unsigned short* cbuf = vtb + NX;

    cast5_kernel<<<dim3(4096, 5), 256, 0, stream>>>(x, Wq, Wk, Wv, Wo,
                                                    xb, wqb, wkb, wvb, wob);
    qkv_mfma<<<dim3(32, 24), 256, 0, stream>>>(xb, wqb, wkb, wvb, qb, kb, vtb);
    attn_mfma<<<dim3(32, 32), 256, 0, stream>>>(qb, kb, vtb, cbuf);
    oproj_mfma<<<dim3(32, 8), 256, 0, stream>>>(cbuf, wob, bo, out);
}

// Round 5
// 228.161 us; speedup vs baseline: 1.3359x; 1.3359x over previous
//
#include <hip/hip_runtime.h>
#include <math.h>

#define BB 2
#define TT 2048
#define DD 1024
#define NH 16
#define HDD 64

typedef __attribute__((ext_vector_type(8))) short v8s;     // 8 bf16 in 4 VGPRs
typedef __attribute__((ext_vector_type(4))) short v4s;     // 4 bf16 in 2 VGPRs
typedef __attribute__((ext_vector_type(4))) float f32x4;   // MFMA C/D

__device__ __forceinline__ unsigned short f2bf(float f) {
    union { float f; unsigned int u; } c; c.f = f;
    unsigned int r = c.u + 0x7FFF + ((c.u >> 16) & 1);     // RNE
    return (unsigned short)(r >> 16);
}

__device__ __forceinline__ void gload_lds16(const void* g, void* l) {
    __builtin_amdgcn_global_load_lds(
        (const __attribute__((address_space(1))) void*)g,
        (__attribute__((address_space(3))) void*)l, 16, 0, 0);
}

// K=16 bf16 MFMA (v_mfma_f32_16x16x16_bf16: A/B = 4 bf16, C/D = 4 f32).
__device__ __forceinline__ f32x4 mfma16x16x16bf16(v4s a, v4s b, f32x4 c) {
#if __has_builtin(__builtin_amdgcn_mfma_f32_16x16x16bf16_1k)
    return __builtin_amdgcn_mfma_f32_16x16x16bf16_1k(a, b, c, 0, 0, 0);
#else
    f32x4 d;
    asm("v_mfma_f32_16x16x16_bf16 %0, %1, %2, %0"
        : "=v"(d) : "v"(a), "v"(b), "0"(c));
    return d;
#endif
}

// ============================================================================
// Cast fp32 -> bf16 for x, Wq, Wk, Wv, Wo (blockIdx.y selects tensor).
// ============================================================================
__global__ __launch_bounds__(256) void cast5_kernel(
    const float* __restrict__ x, const float* __restrict__ wq,
    const float* __restrict__ wk, const float* __restrict__ wv,
    const float* __restrict__ wo,
    unsigned short* __restrict__ xo, unsigned short* __restrict__ wqo,
    unsigned short* __restrict__ wko, unsigned short* __restrict__ wvo,
    unsigned short* __restrict__ woo)
{
    const float* s; unsigned short* d; int n4;
    switch (blockIdx.y) {
        case 0: s = x;  d = xo;  n4 = BB * TT * DD / 4; break;
        case 1: s = wq; d = wqo; n4 = DD * DD / 4; break;
        case 2: s = wk; d = wko; n4 = DD * DD / 4; break;
        case 3: s = wv; d = wvo; n4 = DD * DD / 4; break;
        default: s = wo; d = woo; n4 = DD * DD / 4; break;
    }
    int i = blockIdx.x * 256 + threadIdx.x;
    if (i < n4) {
        float4 v = ((const float4*)s)[i];
        ushort4 o;
        o.x = f2bf(v.x); o.y = f2bf(v.y); o.z = f2bf(v.z); o.w = f2bf(v.w);
        ((ushort4*)d)[i] = o;
    }
}

// ============================================================================
// QKV projection: bf16 MFMA B^T GEMM, 128x128 tile, BK=32, global_load_lds.
// q stored (B,H,T,HD); k stored (B,H,T,HD) PRE-SCALED by 0.125 (folds the
// softmax 1/sqrt(HD), exact pow2); v stored TRANSPOSED (B,H,HD,T).
// q/k epilogue: 2-pass LDS transpose -> coalesced uint4 stores.
// R5 FIX: read-back covers all 32 cols/thread (4 chunks x 8 ushorts; R4's
// 2 chunks x 16-element stride skipped half the columns -> stale q/k).
// ============================================================================
__global__ __launch_bounds__(256) void qkv_mfma(
    const unsigned short* __restrict__ x,
    const unsigned short* __restrict__ wq, const unsigned short* __restrict__ wk,
    const unsigned short* __restrict__ wv,
    unsigned short* __restrict__ qo, unsigned short* __restrict__ ko,
    unsigned short* __restrict__ vo)
{
    __shared__ unsigned short SMEM[8704];     // GEMM: As=SMEM, Bs=SMEM+4096
    unsigned short* As = SMEM;                // epilogue: 64 x (stride 136)
    unsigned short* Bs = SMEM + 4096;

    const int tid = threadIdx.x;
    const int lane = tid & 63;
    const int wid = tid >> 6;
    const int l15 = lane & 15, quad = lane >> 4;

    const int m0 = blockIdx.x << 7;
    const int ny = blockIdx.y;
    const int which = ny >> 3;                // 0=q 1=k 2=v
    const int n0 = (ny & 7) << 7;
    const unsigned short* W = (which == 0) ? wq : (which == 1) ? wk : wv;

    const int wm = (wid >> 1) << 6;
    const int wn = (wid & 1) << 6;

    f32x4 acc[4][4] = {};

    for (int k0 = 0; k0 < DD; k0 += 32) {
        __syncthreads();
#pragma unroll
        for (int u = 0; u < 2; ++u) {
            const int f = (wid << 11) + (u << 10) + (lane << 4);
            const int row = f >> 6;
            const int cs = (f & 63) >> 1;
            gload_lds16(&x[(size_t)(m0 + row) * DD + k0 + cs], ((char*)As) + f);
            gload_lds16(&W[(size_t)(n0 + row) * DD + k0 + cs], ((char*)Bs) + f);
        }
        __syncthreads();

        v8s af[4], bf[4];
#pragma unroll
        for (int i = 0; i < 4; ++i)
            af[i] = *(const v8s*)(((const char*)As) + (wm + (i << 4) + l15) * 64 + (quad << 4));
#pragma unroll
        for (int j = 0; j < 4; ++j)
            bf[j] = *(const v8s*)(((const char*)Bs) + (wn + (j << 4) + l15) * 64 + (quad << 4));
#pragma unroll
        for (int i = 0; i < 4; ++i)
#pragma unroll
            for (int j = 0; j < 4; ++j)
                acc[i][j] = __builtin_amdgcn_mfma_f32_16x16x32_bf16(af[i], bf[j], acc[i][j], 0, 0, 0);
    }

    if (which == 2) {
        // v transposed: (B,H,HD,T); lane's 4 acc rows = consecutive t -> 8B store
#pragma unroll
        for (int i = 0; i < 4; ++i)
#pragma unroll
            for (int j = 0; j < 4; ++j) {
                const int n = n0 + wn + (j << 4) + l15;
                const int h = n >> 6, hd = n & 63;
                const int mb = m0 + wm + (i << 4) + (quad << 2);
                const int b = mb >> 11, t = mb & 2047;
                ushort4 pk;
                pk.x = f2bf(acc[i][j][0]); pk.y = f2bf(acc[i][j][1]);
                pk.z = f2bf(acc[i][j][2]); pk.w = f2bf(acc[i][j][3]);
                *(ushort4*)&vo[((((size_t)(b * NH + h) << 6) + hd) << 11) + t] = pk;
            }
    } else {
        unsigned short* outp = (which == 0) ? qo : ko;
        const float sc = (which == 1) ? 0.125f : 1.0f;
        // two passes of 64 rows: the two waves owning the half-tile write it
        // (bf16) to LDS; all 256 threads read rows back and store coalesced.
#pragma unroll
        for (int p = 0; p < 2; ++p) {
            __syncthreads();
            if ((wid >> 1) == p) {
#pragma unroll
                for (int i = 0; i < 4; ++i)
#pragma unroll
                    for (int j = 0; j < 4; ++j)
#pragma unroll
                        for (int r = 0; r < 4; ++r) {
                            const int row = (i << 4) + (quad << 2) + r;   // 0..63
                            SMEM[row * 136 + wn + (j << 4) + l15] = f2bf(acc[i][j][r] * sc);
                        }
            }
            __syncthreads();
            const int rr = tid >> 2;               // 0..63
            const int cg = (tid & 3) << 5;         // 0,32,64,96 (ushorts)
            const int m = m0 + (p << 6) + rr;
            const int b = m >> 11, t = m & 2047;
#pragma unroll
            for (int k2 = 0; k2 < 4; ++k2) {       // 4 x 8 ushorts = 32 cols
                const int n = n0 + cg + (k2 << 3);
                const int h = n >> 6, hd = n & 63;
                const uint4 val = *(const uint4*)&SMEM[rr * 136 + cg + (k2 << 3)];
                *(uint4*)&outp[(((size_t)(b * NH + h) * TT + t) << 6) + hd] = val;
            }
        }
    }
}

// ============================================================================
// Flash attention, bf16 MFMA, S^T formulation:
//   St[64k x 16q] = K . Q^T  -> C-layout puts one q-row per lane (col=l15):
//   softmax = 15 in-reg ops + 2 shfl;  P^T chunks == B-frags of K=16 MFMA
//   -> PV = O^T += Vt . P^T with no LDS round trip.
// Paired q-tiles {x,31-x} (512 blocks, uniform 33 k-tiles/block), direct
// uint4 staging, no register prefetch (R3's prefetch caused scratch spills).
// ============================================================================
__global__ __launch_bounds__(256) void attn_mfma(
    const unsigned short* __restrict__ q, const unsigned short* __restrict__ k,
    const unsigned short* __restrict__ vt, unsigned short* __restrict__ ctx)
{
    __shared__ unsigned short Qs[64][72];
    __shared__ unsigned short Ks[64][72];
    __shared__ unsigned short Vts[64][72];

    const int tid = threadIdx.x;
    const int lane = tid & 63;
    const int wid = tid >> 6;
    const int l15 = lane & 15, quad = lane >> 4;
    const int bh = blockIdx.y;

    const unsigned short* qb = q + (size_t)bh * TT * HDD;
    const unsigned short* kb = k + (size_t)bh * TT * HDD;
    const unsigned short* vb = vt + (size_t)bh * HDD * TT;   // (HD, T)
    unsigned short* cb = ctx + (size_t)bh * TT * HDD;

    const int cr = tid >> 3;            // staging row 0..31 (x2 rounds)
    const int cc = (tid & 7) << 3;      // staging col (ushort), 16B chunks

    for (int half = 0; half < 2; ++half) {
        const int qt = half ? (31 - (int)blockIdx.x) : (int)blockIdx.x;
        const int q0 = qt << 6;
        const int qrow = q0 + (wid << 4) + l15;   // this lane's q-row

        __syncthreads();                // prev-half LDS reads done
#pragma unroll
        for (int u = 0; u < 2; ++u) {
            const int r = cr + (u << 5);
            *(uint4*)&Qs[r][cc] = *(const uint4*)&qb[(size_t)(q0 + r) * HDD + cc];
        }
        __syncthreads();

        // Q B-frags (B-frag(Q^T) reads Q rows), wave-resident for the k-loop
        v8s qf[2];
#pragma unroll
        for (int c = 0; c < 2; ++c)
            qf[c] = *(const v8s*)&Qs[(wid << 4) + l15][(c << 5) + (quad << 3)];

        float m_i = -INFINITY, l_i = 0.f;
        f32x4 o[4] = {};                // O^T: d = m*16 + quad*4 + r, col q=l15

        for (int jt = 0; jt <= qt; ++jt) {
            const int k0 = jt << 6;
            __syncthreads();            // prev-tile LDS reads complete
#pragma unroll
            for (int u = 0; u < 2; ++u) {
                const int r = cr + (u << 5);
                *(uint4*)&Ks[r][cc] = *(const uint4*)&kb[(size_t)(k0 + r) * HDD + cc];
                *(uint4*)&Vts[r][cc] = *(const uint4*)&vb[((size_t)r << 11) + k0 + cc];
            }
            __syncthreads();

            // S^T = K . Q^T : St[k = m*16+quad*4+r][q = l15]  (K pre-scaled)
            f32x4 s[4] = {};
#pragma unroll
            for (int m = 0; m < 4; ++m) {
                const v8s kf0 = *(const v8s*)&Ks[(m << 4) + l15][quad << 3];
                const v8s kf1 = *(const v8s*)&Ks[(m << 4) + l15][32 + (quad << 3)];
                s[m] = __builtin_amdgcn_mfma_f32_16x16x32_bf16(kf0, qf[0], s[m], 0, 0, 0);
                s[m] = __builtin_amdgcn_mfma_f32_16x16x32_bf16(kf1, qf[1], s[m], 0, 0, 0);
            }

            if (jt == qt) {             // causal mask, diagonal tile only
#pragma unroll
                for (int m = 0; m < 4; ++m) {
                    const int kc = k0 + (m << 4) + (quad << 2);
#pragma unroll
                    for (int r = 0; r < 4; ++r)
                        if (kc + r > qrow) s[m][r] = -INFINITY;
                }
            }

            // online softmax: one q-row per lane (16 in-reg values, 2 shfl)
            float mx = fmaxf(fmaxf(s[0][0], s[0][1]), fmaxf(s[0][2], s[0][3]));
            mx = fmaxf(mx, fmaxf(fmaxf(s[1][0], s[1][1]), fmaxf(s[1][2], s[1][3])));
            mx = fmaxf(mx, fmaxf(fmaxf(s[2][0], s[2][1]), fmaxf(s[2][2], s[2][3])));
            mx = fmaxf(mx, fmaxf(fmaxf(s[3][0], s[3][1]), fmaxf(s[3][2], s[3][3])));
            mx = fmaxf(mx, __shfl_xor(mx, 16));
            mx = fmaxf(mx, __shfl_xor(mx, 32));
            const float m_new = fmaxf(m_i, mx);
            const float alpha = __expf(m_i - m_new);
            m_i = m_new;

            float sum = 0.f;
            v4s pf[4];
#pragma unroll
            for (int m = 0; m < 4; ++m) {
                v4s t;
#pragma unroll
                for (int r = 0; r < 4; ++r) {
                    const float pv = __expf(s[m][r] - m_new);
                    sum += pv;
                    t[r] = (short)f2bf(pv);
                }
                pf[m] = t;
            }
            sum += __shfl_xor(sum, 16);
            sum += __shfl_xor(sum, 32);
            l_i = l_i * alpha + sum;

#pragma unroll
            for (int m = 0; m < 4; ++m)
#pragma unroll
                for (int r = 0; r < 4; ++r)
                    o[m][r] *= alpha;

            // O^T += Vt . P^T   (A = Vt 16x16 chunk, B = P^T chunk from regs)
#pragma unroll
            for (int m = 0; m < 4; ++m)
#pragma unroll
                for (int c = 0; c < 4; ++c) {
                    const v4s vf = *(const v4s*)&Vts[(m << 4) + l15][(c << 4) + (quad << 2)];
                    o[m] = mfma16x16x16bf16(vf, pf[c], o[m]);
                }
        }

        // normalize + store: ctx[q][d], d = m*16 + quad*4 + r (8B stores)
        const float linv = 1.f / l_i;
#pragma unroll
        for (int m = 0; m < 4; ++m) {
            ushort4 st;
            st.x = f2bf(o[m][0] * linv); st.y = f2bf(o[m][1] * linv);
            st.z = f2bf(o[m][2] * linv); st.w = f2bf(o[m][3] * linv);
            *(ushort4*)&cb[((size_t)qrow << 6) + (m << 4) + (quad << 2)] = st;
        }
    }
}

// ============================================================================
// Output projection: ctx (bf16, flat 4096x1024 = faithful reshape) x Wo^T + bo
// ============================================================================
__global__ __launch_bounds__(256) void oproj_mfma(
    const unsigned short* __restrict__ c, const unsigned short* __restrict__ wo,
    const float* __restrict__ bo, float* __restrict__ out)
{
    __shared__ unsigned short As[128 * 32];
    __shared__ unsigned short Bs[128 * 32];

    const int tid = threadIdx.x;
    const int lane = tid & 63;
    const int wid = tid >> 6;
    const int l15 = lane & 15, quad = lane >> 4;

    const int m0 = blockIdx.x << 7;
    const int n0 = blockIdx.y << 7;
    const int wm = (wid >> 1) << 6, wn = (wid & 1) << 6;

    f32x4 acc[4][4] = {};

    for (int k0 = 0; k0 < DD; k0 += 32) {
        __syncthreads();
#pragma unroll
        for (int u = 0; u < 2; ++u) {
            const int f = (wid << 11) + (u << 10) + (lane << 4);
            const int row = f >> 6;
            const int cs = (f & 63) >> 1;
            gload_lds16(&c[(size_t)(m0 + row) * DD + k0 + cs], ((char*)As) + f);
            gload_lds16(&wo[(size_t)(n0 + row) * DD + k0 + cs], ((char*)Bs) + f);
        }
        __syncthreads();

        v8s af[4], bf[4];
#pragma unroll
        for (int i = 0; i < 4; ++i)
            af[i] = *(const v8s*)(((const char*)As) + (wm + (i << 4) + l15) * 64 + (quad << 4));
#pragma unroll
        for (int j = 0; j < 4; ++j)
            bf[j] = *(const v8s*)(((const char*)Bs) + (wn + (j << 4) + l15) * 64 + (quad << 4));
#pragma unroll
        for (int i = 0; i < 4; ++i)
#pragma unroll
            for (int j = 0; j < 4; ++j)
                acc[i][j] = __builtin_amdgcn_mfma_f32_16x16x32_bf16(af[i], bf[j], acc[i][j], 0, 0, 0);
    }

#pragma unroll
    for (int j = 0; j < 4; ++j) {
        const int n = n0 + wn + (j << 4) + l15;
        const float bias = bo[n];
#pragma unroll
        for (int i = 0; i < 4; ++i) {
            const int mb = m0 + wm + (i << 4) + (quad << 2);
#pragma unroll
            for (int r = 0; r < 4; ++r)
                out[(size_t)(mb + r) * DD + n] = acc[i][j][r] + bias;
        }
    }
}

extern "C" void kernel_launch(void* const* d_in, const int* in_sizes, int n_in,
                              void* d_out, int out_size, void* d_ws, size_t ws_size,
                              hipStream_t stream) {
    const float* x  = (const float*)d_in[0];
    const float* Wq = (const float*)d_in[1];
    const float* Wk = (const float*)d_in[2];
    const float* Wv = (const float*)d_in[3];
    const float* Wo = (const float*)d_in[4];
    const float* bo = (const float*)d_in[5];
    float* out = (float*)d_out;

    const size_t NX = (size_t)BB * TT * DD;
    const size_t NW = (size_t)DD * DD;

    unsigned short* xb  = (unsigned short*)d_ws;
    unsigned short* wqb = xb + NX;
    unsigned short* wkb = wqb + NW;
    unsigned short* wvb = wkb + NW;
    unsigned short* wob = wvb + NW;
    unsigned short* qb  = wob + NW;
    unsigned short* kb  = qb + NX;
    unsigned short* vtb = kb + NX;
    unsigned short* cbuf = vtb + NX;

    cast5_kernel<<<dim3(4096, 5), 256, 0, stream>>>(x, Wq, Wk, Wv, Wo,
                                                    xb, wqb, wkb, wvb, wob);
    qkv_mfma<<<dim3(32, 24), 256, 0, stream>>>(xb, wqb, wkb, wvb, qb, kb, vtb);
    attn_mfma<<<dim3(16, 32), 256, 0, stream>>>(qb, kb, vtb, cbuf);
    oproj_mfma<<<dim3(32, 8), 256, 0, stream>>>(cbuf, wob, bo, out);
}

// Round 6
// 196.389 us; speedup vs baseline: 1.5520x; 1.1618x over previous
//
#include <hip/hip_runtime.h>
#include <math.h>

#define BB 2
#define TT 2048
#define DD 1024
#define NH 16
#define HDD 64

typedef __attribute__((ext_vector_type(8))) short v8s;     // 8 bf16 in 4 VGPRs
typedef __attribute__((ext_vector_type(4))) short v4s;     // 4 bf16 in 2 VGPRs
typedef __attribute__((ext_vector_type(4))) float f32x4;   // MFMA C/D

__device__ __forceinline__ unsigned short f2bf(float f) {
    union { float f; unsigned int u; } c; c.f = f;
    unsigned int r = c.u + 0x7FFF + ((c.u >> 16) & 1);     // RNE
    return (unsigned short)(r >> 16);
}

__device__ __forceinline__ void gload_lds16(const void* g, void* l) {
    __builtin_amdgcn_global_load_lds(
        (const __attribute__((address_space(1))) void*)g,
        (__attribute__((address_space(3))) void*)l, 16, 0, 0);
}

// K=16 bf16 MFMA (v_mfma_f32_16x16x16_bf16: A/B = 4 bf16, C/D = 4 f32).
__device__ __forceinline__ f32x4 mfma16x16x16bf16(v4s a, v4s b, f32x4 c) {
#if __has_builtin(__builtin_amdgcn_mfma_f32_16x16x16bf16_1k)
    return __builtin_amdgcn_mfma_f32_16x16x16bf16_1k(a, b, c, 0, 0, 0);
#else
    f32x4 d;
    asm("v_mfma_f32_16x16x16_bf16 %0, %1, %2, %0"
        : "=v"(d) : "v"(a), "v"(b), "0"(c));
    return d;
#endif
}

// ============================================================================
// Cast fp32 -> bf16 for x, Wq, Wk, Wv, Wo (blockIdx.y selects tensor).
// (unchanged from R5)
// ============================================================================
__global__ __launch_bounds__(256) void cast5_kernel(
    const float* __restrict__ x, const float* __restrict__ wq,
    const float* __restrict__ wk, const float* __restrict__ wv,
    const float* __restrict__ wo,
    unsigned short* __restrict__ xo, unsigned short* __restrict__ wqo,
    unsigned short* __restrict__ wko, unsigned short* __restrict__ wvo,
    unsigned short* __restrict__ woo)
{
    const float* s; unsigned short* d; int n4;
    switch (blockIdx.y) {
        case 0: s = x;  d = xo;  n4 = BB * TT * DD / 4; break;
        case 1: s = wq; d = wqo; n4 = DD * DD / 4; break;
        case 2: s = wk; d = wko; n4 = DD * DD / 4; break;
        case 3: s = wv; d = wvo; n4 = DD * DD / 4; break;
        default: s = wo; d = woo; n4 = DD * DD / 4; break;
    }
    int i = blockIdx.x * 256 + threadIdx.x;
    if (i < n4) {
        float4 v = ((const float4*)s)[i];
        ushort4 o;
        o.x = f2bf(v.x); o.y = f2bf(v.y); o.z = f2bf(v.z); o.w = f2bf(v.w);
        ((ushort4*)d)[i] = o;
    }
}

// ============================================================================
// QKV projection: bf16 MFMA B^T GEMM, 128x128 tile, BK=32.
// R6: DOUBLE-BUFFERED LDS K-loop — global_load_lds for tile t+1 issued
// before computing tile t; ONE barrier per iteration.  The vmcnt(0) drain
// at the barrier now happens after a full compute phase, hiding the
// global-load latency that made R5's 2-barrier loop 85% idle.
// LDS layout (bytes): As0 @0, As1 @8192, Bs0 @16384, Bs1 @24576 (32 KB).
// Epilogue transpose overlays bytes [0, 17408) after the final barrier.
// q (B,H,T,HD); k (B,H,T,HD) pre-scaled 0.125; v transposed (B,H,HD,T).
// ============================================================================
__global__ __launch_bounds__(256) void qkv_mfma(
    const unsigned short* __restrict__ x,
    const unsigned short* __restrict__ wq, const unsigned short* __restrict__ wk,
    const unsigned short* __restrict__ wv,
    unsigned short* __restrict__ qo, unsigned short* __restrict__ ko,
    unsigned short* __restrict__ vo)
{
    __shared__ unsigned short SMEM[16384];    // 32 KB

    const int tid = threadIdx.x;
    const int lane = tid & 63;
    const int wid = tid >> 6;
    const int l15 = lane & 15, quad = lane >> 4;

    const int m0 = blockIdx.x << 7;
    const int ny = blockIdx.y;
    const int which = ny >> 3;                // 0=q 1=k 2=v
    const int n0 = (ny & 7) << 7;
    const unsigned short* W = (which == 0) ? wq : (which == 1) ? wk : wv;

    const int wm = (wid >> 1) << 6;
    const int wn = (wid & 1) << 6;

    // staging geometry (per thread, 2 chunks of 16B per tensor)
    const int f0 = (wid << 11) + (lane << 4);          // u=0 byte offset
    const int row0 = f0 >> 6, cs0 = (f0 & 63) >> 1;
    const int f1 = f0 + 1024;                          // u=1
    const int row1 = f1 >> 6, cs1 = (f1 & 63) >> 1;

    char* const smem = (char*)SMEM;

#define QKV_STAGE(k0, buf)                                                     \
    do {                                                                       \
        gload_lds16(&x[(size_t)(m0 + row0) * DD + (k0) + cs0],                 \
                    smem + (buf) * 8192 + f0);                                 \
        gload_lds16(&x[(size_t)(m0 + row1) * DD + (k0) + cs1],                 \
                    smem + (buf) * 8192 + f1);                                 \
        gload_lds16(&W[(size_t)(n0 + row0) * DD + (k0) + cs0],                 \
                    smem + 16384 + (buf) * 8192 + f0);                         \
        gload_lds16(&W[(size_t)(n0 + row1) * DD + (k0) + cs1],                 \
                    smem + 16384 + (buf) * 8192 + f1);                         \
    } while (0)

    f32x4 acc[4][4] = {};

    QKV_STAGE(0, 0);
    __syncthreads();                          // buf0 ready

    int cur = 0;
    for (int k0 = 0; k0 < DD; k0 += 32) {
        if (k0 + 32 < DD) QKV_STAGE(k0 + 32, cur ^ 1);   // async prefetch

        const char* Ab = smem + cur * 8192;
        const char* Bb = smem + 16384 + cur * 8192;
        v8s af[4], bf[4];
#pragma unroll
        for (int i = 0; i < 4; ++i)
            af[i] = *(const v8s*)(Ab + (wm + (i << 4) + l15) * 64 + (quad << 4));
#pragma unroll
        for (int j = 0; j < 4; ++j)
            bf[j] = *(const v8s*)(Bb + (wn + (j << 4) + l15) * 64 + (quad << 4));
#pragma unroll
        for (int i = 0; i < 4; ++i)
#pragma unroll
            for (int j = 0; j < 4; ++j)
                acc[i][j] = __builtin_amdgcn_mfma_f32_16x16x32_bf16(af[i], bf[j], acc[i][j], 0, 0, 0);

        __syncthreads();                      // publish prefetch, retire reads
        cur ^= 1;
    }
#undef QKV_STAGE

    if (which == 2) {
        // v transposed: (B,H,HD,T); lane's 4 acc rows = consecutive t -> 8B store
#pragma unroll
        for (int i = 0; i < 4; ++i)
#pragma unroll
            for (int j = 0; j < 4; ++j) {
                const int n = n0 + wn + (j << 4) + l15;
                const int h = n >> 6, hd = n & 63;
                const int mb = m0 + wm + (i << 4) + (quad << 2);
                const int b = mb >> 11, t = mb & 2047;
                ushort4 pk;
                pk.x = f2bf(acc[i][j][0]); pk.y = f2bf(acc[i][j][1]);
                pk.z = f2bf(acc[i][j][2]); pk.w = f2bf(acc[i][j][3]);
                *(ushort4*)&vo[((((size_t)(b * NH + h) << 6) + hd) << 11) + t] = pk;
            }
    } else {
        unsigned short* outp = (which == 0) ? qo : ko;
        const float sc = (which == 1) ? 0.125f : 1.0f;
        // two passes of 64 rows: the two waves owning the half-tile write it
        // (bf16) to LDS; all 256 threads read rows back and store coalesced.
#pragma unroll
        for (int p = 0; p < 2; ++p) {
            __syncthreads();
            if ((wid >> 1) == p) {
#pragma unroll
                for (int i = 0; i < 4; ++i)
#pragma unroll
                    for (int j = 0; j < 4; ++j)
#pragma unroll
                        for (int r = 0; r < 4; ++r) {
                            const int row = (i << 4) + (quad << 2) + r;   // 0..63
                            SMEM[row * 136 + wn + (j << 4) + l15] = f2bf(acc[i][j][r] * sc);
                        }
            }
            __syncthreads();
            const int rr = tid >> 2;               // 0..63
            const int cg = (tid & 3) << 5;         // 0,32,64,96 (ushorts)
            const int m = m0 + (p << 6) + rr;
            const int b = m >> 11, t = m & 2047;
#pragma unroll
            for (int k2 = 0; k2 < 4; ++k2) {       // 4 x 8 ushorts = 32 cols
                const int n = n0 + cg + (k2 << 3);
                const int h = n >> 6, hd = n & 63;
                const uint4 val = *(const uint4*)&SMEM[rr * 136 + cg + (k2 << 3)];
                *(uint4*)&outp[(((size_t)(b * NH + h) * TT + t) << 6) + hd] = val;
            }
        }
    }
}

// ============================================================================
// Flash attention, bf16 MFMA, S^T formulation.  (unchanged from R5 — attn was
// not in the R5 top-5; keeping it fixed isolates this round's qkv/oproj change)
// ============================================================================
__global__ __launch_bounds__(256) void attn_mfma(
    const unsigned short* __restrict__ q, const unsigned short* __restrict__ k,
    const unsigned short* __restrict__ vt, unsigned short* __restrict__ ctx)
{
    __shared__ unsigned short Qs[64][72];
    __shared__ unsigned short Ks[64][72];
    __shared__ unsigned short Vts[64][72];

    const int tid = threadIdx.x;
    const int lane = tid & 63;
    const int wid = tid >> 6;
    const int l15 = lane & 15, quad = lane >> 4;
    const int bh = blockIdx.y;

    const unsigned short* qb = q + (size_t)bh * TT * HDD;
    const unsigned short* kb = k + (size_t)bh * TT * HDD;
    const unsigned short* vb = vt + (size_t)bh * HDD * TT;   // (HD, T)
    unsigned short* cb = ctx + (size_t)bh * TT * HDD;

    const int cr = tid >> 3;            // staging row 0..31 (x2 rounds)
    const int cc = (tid & 7) << 3;      // staging col (ushort), 16B chunks

    for (int half = 0; half < 2; ++half) {
        const int qt = half ? (31 - (int)blockIdx.x) : (int)blockIdx.x;
        const int q0 = qt << 6;
        const int qrow = q0 + (wid << 4) + l15;   // this lane's q-row

        __syncthreads();                // prev-half LDS reads done
#pragma unroll
        for (int u = 0; u < 2; ++u) {
            const int r = cr + (u << 5);
            *(uint4*)&Qs[r][cc] = *(const uint4*)&qb[(size_t)(q0 + r) * HDD + cc];
        }
        __syncthreads();

        // Q B-frags (B-frag(Q^T) reads Q rows), wave-resident for the k-loop
        v8s qf[2];
#pragma unroll
        for (int c = 0; c < 2; ++c)
            qf[c] = *(const v8s*)&Qs[(wid << 4) + l15][(c << 5) + (quad << 3)];

        float m_i = -INFINITY, l_i = 0.f;
        f32x4 o[4] = {};                // O^T: d = m*16 + quad*4 + r, col q=l15

        for (int jt = 0; jt <= qt; ++jt) {
            const int k0 = jt << 6;
            __syncthreads();            // prev-tile LDS reads complete
#pragma unroll
            for (int u = 0; u < 2; ++u) {
                const int r = cr + (u << 5);
                *(uint4*)&Ks[r][cc] = *(const uint4*)&kb[(size_t)(k0 + r) * HDD + cc];
                *(uint4*)&Vts[r][cc] = *(const uint4*)&vb[((size_t)r << 11) + k0 + cc];
            }
            __syncthreads();

            // S^T = K . Q^T : St[k = m*16+quad*4+r][q = l15]  (K pre-scaled)
            f32x4 s[4] = {};
#pragma unroll
            for (int m = 0; m < 4; ++m) {
                const v8s kf0 = *(const v8s*)&Ks[(m << 4) + l15][quad << 3];
                const v8s kf1 = *(const v8s*)&Ks[(m << 4) + l15][32 + (quad << 3)];
                s[m] = __builtin_amdgcn_mfma_f32_16x16x32_bf16(kf0, qf[0], s[m], 0, 0, 0);
                s[m] = __builtin_amdgcn_mfma_f32_16x16x32_bf16(kf1, qf[1], s[m], 0, 0, 0);
            }

            if (jt == qt) {             // causal mask, diagonal tile only
#pragma unroll
                for (int m = 0; m < 4; ++m) {
                    const int kc = k0 + (m << 4) + (quad << 2);
#pragma unroll
                    for (int r = 0; r < 4; ++r)
                        if (kc + r > qrow) s[m][r] = -INFINITY;
                }
            }

            // online softmax: one q-row per lane (16 in-reg values, 2 shfl)
            float mx = fmaxf(fmaxf(s[0][0], s[0][1]), fmaxf(s[0][2], s[0][3]));
            mx = fmaxf(mx, fmaxf(fmaxf(s[1][0], s[1][1]), fmaxf(s[1][2], s[1][3])));
            mx = fmaxf(mx, fmaxf(fmaxf(s[2][0], s[2][1]), fmaxf(s[2][2], s[2][3])));
            mx = fmaxf(mx, fmaxf(fmaxf(s[3][0], s[3][1]), fmaxf(s[3][2], s[3][3])));
            mx = fmaxf(mx, __shfl_xor(mx, 16));
            mx = fmaxf(mx, __shfl_xor(mx, 32));
            const float m_new = fmaxf(m_i, mx);
            const float alpha = __expf(m_i - m_new);
            m_i = m_new;

            float sum = 0.f;
            v4s pf[4];
#pragma unroll
            for (int m = 0; m < 4; ++m) {
                v4s t;
#pragma unroll
                for (int r = 0; r < 4; ++r) {
                    const float pv = __expf(s[m][r] - m_new);
                    sum += pv;
                    t[r] = (short)f2bf(pv);
                }
                pf[m] = t;
            }
            sum += __shfl_xor(sum, 16);
            sum += __shfl_xor(sum, 32);
            l_i = l_i * alpha + sum;

#pragma unroll
            for (int m = 0; m < 4; ++m)
#pragma unroll
                for (int r = 0; r < 4; ++r)
                    o[m][r] *= alpha;

            // O^T += Vt . P^T   (A = Vt 16x16 chunk, B = P^T chunk from regs)
#pragma unroll
            for (int m = 0; m < 4; ++m)
#pragma unroll
                for (int c = 0; c < 4; ++c) {
                    const v4s vf = *(const v4s*)&Vts[(m << 4) + l15][(c << 4) + (quad << 2)];
                    o[m] = mfma16x16x16bf16(vf, pf[c], o[m]);
                }
        }

        // normalize + store: ctx[q][d], d = m*16 + quad*4 + r (8B stores)
        const float linv = 1.f / l_i;
#pragma unroll
        for (int m = 0; m < 4; ++m) {
            ushort4 st;
            st.x = f2bf(o[m][0] * linv); st.y = f2bf(o[m][1] * linv);
            st.z = f2bf(o[m][2] * linv); st.w = f2bf(o[m][3] * linv);
            *(ushort4*)&cb[((size_t)qrow << 6) + (m << 4) + (quad << 2)] = st;
        }
    }
}

// ============================================================================
// Output projection: ctx (bf16, flat 4096x1024 = faithful reshape) x Wo^T + bo
// R6: same double-buffered LDS K-loop as qkv_mfma.
// ============================================================================
__global__ __launch_bounds__(256) void oproj_mfma(
    const unsigned short* __restrict__ c, const unsigned short* __restrict__ wo,
    const float* __restrict__ bo, float* __restrict__ out)
{
    __shared__ unsigned short SMEM[16384];    // 32 KB

    const int tid = threadIdx.x;
    const int lane = tid & 63;
    const int wid = tid >> 6;
    const int l15 = lane & 15, quad = lane >> 4;

    const int m0 = blockIdx.x << 7;
    const int n0 = blockIdx.y << 7;
    const int wm = (wid >> 1) << 6, wn = (wid & 1) << 6;

    const int f0 = (wid << 11) + (lane << 4);
    const int row0 = f0 >> 6, cs0 = (f0 & 63) >> 1;
    const int f1 = f0 + 1024;
    const int row1 = f1 >> 6, cs1 = (f1 & 63) >> 1;

    char* const smem = (char*)SMEM;

#define OP_STAGE(k0, buf)                                                      \
    do {                                                                       \
        gload_lds16(&c[(size_t)(m0 + row0) * DD + (k0) + cs0],                 \
                    smem + (buf) * 8192 + f0);                                 \
        gload_lds16(&c[(size_t)(m0 + row1) * DD + (k0) + cs1],                 \
                    smem + (buf) * 8192 + f1);                                 \
        gload_lds16(&wo[(size_t)(n0 + row0) * DD + (k0) + cs0],                \
                    smem + 16384 + (buf) * 8192 + f0);                         \
        gload_lds16(&wo[(size_t)(n0 + row1) * DD + (k0) + cs1],                \
                    smem + 16384 + (buf) * 8192 + f1);                         \
    } while (0)

    f32x4 acc[4][4] = {};

    OP_STAGE(0, 0);
    __syncthreads();

    int cur = 0;
    for (int k0 = 0; k0 < DD; k0 += 32) {
        if (k0 + 32 < DD) OP_STAGE(k0 + 32, cur ^ 1);

        const char* Ab = smem + cur * 8192;
        const char* Bb = smem + 16384 + cur * 8192;
        v8s af[4], bf[4];
#pragma unroll
        for (int i = 0; i < 4; ++i)
            af[i] = *(const v8s*)(Ab + (wm + (i << 4) + l15) * 64 + (quad << 4));
#pragma unroll
        for (int j = 0; j < 4; ++j)
            bf[j] = *(const v8s*)(Bb + (wn + (j << 4) + l15) * 64 + (quad << 4));
#pragma unroll
        for (int i = 0; i < 4; ++i)
#pragma unroll
            for (int j = 0; j < 4; ++j)
                acc[i][j] = __builtin_amdgcn_mfma_f32_16x16x32_bf16(af[i], bf[j], acc[i][j], 0, 0, 0);

        __syncthreads();
        cur ^= 1;
    }
#undef OP_STAGE

#pragma unroll
    for (int j = 0; j < 4; ++j) {
        const int n = n0 + wn + (j << 4) + l15;
        const float bias = bo[n];
#pragma unroll
        for (int i = 0; i < 4; ++i) {
            const int mb = m0 + wm + (i << 4) + (quad << 2);
#pragma unroll
            for (int r = 0; r < 4; ++r)
                out[(size_t)(mb + r) * DD + n] = acc[i][j][r] + bias;
        }
    }
}

extern "C" void kernel_launch(void* const* d_in, const int* in_sizes, int n_in,
                              void* d_out, int out_size, void* d_ws, size_t ws_size,
                              hipStream_t stream) {
    const float* x  = (const float*)d_in[0];
    const float* Wq = (const float*)d_in[1];
    const float* Wk = (const float*)d_in[2];
    const float* Wv = (const float*)d_in[3];
    const float* Wo = (const float*)d_in[4];
    const float* bo = (const float*)d_in[5];
    float* out = (float*)d_out;

    const size_t NX = (size_t)BB * TT * DD;
    const size_t NW = (size_t)DD * DD;

    unsigned short* xb  = (unsigned short*)d_ws;
    unsigned short* wqb = xb + NX;
    unsigned short* wkb = wqb + NW;
    unsigned short* wvb = wkb + NW;
    unsigned short* wob = wvb + NW;
    unsigned short* qb  = wob + NW;
    unsigned short* kb  = qb + NX;
    unsigned short* vtb = kb + NX;
    unsigned short* cbuf = vtb + NX;

    cast5_kernel<<<dim3(4096, 5), 256, 0, stream>>>(x, Wq, Wk, Wv, Wo,
                                                    xb, wqb, wkb, wvb, wob);
    qkv_mfma<<<dim3(32, 24), 256, 0, stream>>>(xb, wqb, wkb, wvb, qb, kb, vtb);
    attn_mfma<<<dim3(16, 32), 256, 0, stream>>>(qb, kb, vtb, cbuf);
    oproj_mfma<<<dim3(32, 8), 256, 0, stream>>>(cbuf, wob, bo, out);
}

// Round 7
// 190.342 us; speedup vs baseline: 1.6013x; 1.0318x over previous
//
#include <hip/hip_runtime.h>
#include <math.h>

#define BB 2
#define TT 2048
#define DD 1024
#define NH 16
#define HDD 64

typedef __attribute__((ext_vector_type(8))) short v8s;     // 8 bf16 in 4 VGPRs
typedef __attribute__((ext_vector_type(4))) short v4s;     // 4 bf16 in 2 VGPRs
typedef __attribute__((ext_vector_type(4))) float f32x4;   // MFMA C/D

__device__ __forceinline__ unsigned short f2bf(float f) {
    union { float f; unsigned int u; } c; c.f = f;
    unsigned int r = c.u + 0x7FFF + ((c.u >> 16) & 1);     // RNE
    return (unsigned short)(r >> 16);
}

__device__ __forceinline__ void gload_lds16(const void* g, void* l) {
    __builtin_amdgcn_global_load_lds(
        (const __attribute__((address_space(1))) void*)g,
        (__attribute__((address_space(3))) void*)l, 16, 0, 0);
}

// K=16 bf16 MFMA (v_mfma_f32_16x16x16_bf16: A/B = 4 bf16, C/D = 4 f32).
__device__ __forceinline__ f32x4 mfma16x16x16bf16(v4s a, v4s b, f32x4 c) {
#if __has_builtin(__builtin_amdgcn_mfma_f32_16x16x16bf16_1k)
    return __builtin_amdgcn_mfma_f32_16x16x16bf16_1k(a, b, c, 0, 0, 0);
#else
    f32x4 d;
    asm("v_mfma_f32_16x16x16_bf16 %0, %1, %2, %0"
        : "=v"(d) : "v"(a), "v"(b), "0"(c));
    return d;
#endif
}

// ============================================================================
// Cast fp32 -> bf16 for x, Wq, Wk, Wv, Wo (blockIdx.y selects tensor).
// (unchanged)
// ============================================================================
__global__ __launch_bounds__(256) void cast5_kernel(
    const float* __restrict__ x, const float* __restrict__ wq,
    const float* __restrict__ wk, const float* __restrict__ wv,
    const float* __restrict__ wo,
    unsigned short* __restrict__ xo, unsigned short* __restrict__ wqo,
    unsigned short* __restrict__ wko, unsigned short* __restrict__ wvo,
    unsigned short* __restrict__ woo)
{
    const float* s; unsigned short* d; int n4;
    switch (blockIdx.y) {
        case 0: s = x;  d = xo;  n4 = BB * TT * DD / 4; break;
        case 1: s = wq; d = wqo; n4 = DD * DD / 4; break;
        case 2: s = wk; d = wko; n4 = DD * DD / 4; break;
        case 3: s = wv; d = wvo; n4 = DD * DD / 4; break;
        default: s = wo; d = woo; n4 = DD * DD / 4; break;
    }
    int i = blockIdx.x * 256 + threadIdx.x;
    if (i < n4) {
        float4 v = ((const float4*)s)[i];
        ushort4 o;
        o.x = f2bf(v.x); o.y = f2bf(v.y); o.z = f2bf(v.z); o.w = f2bf(v.w);
        ((ushort4*)d)[i] = o;
    }
}

// ============================================================================
// QKV projection (unchanged from R6: double-buffered global_load_lds K-loop).
// ============================================================================
__global__ __launch_bounds__(256) void qkv_mfma(
    const unsigned short* __restrict__ x,
    const unsigned short* __restrict__ wq, const unsigned short* __restrict__ wk,
    const unsigned short* __restrict__ wv,
    unsigned short* __restrict__ qo, unsigned short* __restrict__ ko,
    unsigned short* __restrict__ vo)
{
    __shared__ unsigned short SMEM[16384];    // 32 KB

    const int tid = threadIdx.x;
    const int lane = tid & 63;
    const int wid = tid >> 6;
    const int l15 = lane & 15, quad = lane >> 4;

    const int m0 = blockIdx.x << 7;
    const int ny = blockIdx.y;
    const int which = ny >> 3;                // 0=q 1=k 2=v
    const int n0 = (ny & 7) << 7;
    const unsigned short* W = (which == 0) ? wq : (which == 1) ? wk : wv;

    const int wm = (wid >> 1) << 6;
    const int wn = (wid & 1) << 6;

    const int f0 = (wid << 11) + (lane << 4);
    const int row0 = f0 >> 6, cs0 = (f0 & 63) >> 1;
    const int f1 = f0 + 1024;
    const int row1 = f1 >> 6, cs1 = (f1 & 63) >> 1;

    char* const smem = (char*)SMEM;

#define QKV_STAGE(k0, buf)                                                     \
    do {                                                                       \
        gload_lds16(&x[(size_t)(m0 + row0) * DD + (k0) + cs0],                 \
                    smem + (buf) * 8192 + f0);                                 \
        gload_lds16(&x[(size_t)(m0 + row1) * DD + (k0) + cs1],                 \
                    smem + (buf) * 8192 + f1);                                 \
        gload_lds16(&W[(size_t)(n0 + row0) * DD + (k0) + cs0],                 \
                    smem + 16384 + (buf) * 8192 + f0);                         \
        gload_lds16(&W[(size_t)(n0 + row1) * DD + (k0) + cs1],                 \
                    smem + 16384 + (buf) * 8192 + f1);                         \
    } while (0)

    f32x4 acc[4][4] = {};

    QKV_STAGE(0, 0);
    __syncthreads();

    int cur = 0;
    for (int k0 = 0; k0 < DD; k0 += 32) {
        if (k0 + 32 < DD) QKV_STAGE(k0 + 32, cur ^ 1);

        const char* Ab = smem + cur * 8192;
        const char* Bb = smem + 16384 + cur * 8192;
        v8s af[4], bf[4];
#pragma unroll
        for (int i = 0; i < 4; ++i)
            af[i] = *(const v8s*)(Ab + (wm + (i << 4) + l15) * 64 + (quad << 4));
#pragma unroll
        for (int j = 0; j < 4; ++j)
            bf[j] = *(const v8s*)(Bb + (wn + (j << 4) + l15) * 64 + (quad << 4));
#pragma unroll
        for (int i = 0; i < 4; ++i)
#pragma unroll
            for (int j = 0; j < 4; ++j)
                acc[i][j] = __builtin_amdgcn_mfma_f32_16x16x32_bf16(af[i], bf[j], acc[i][j], 0, 0, 0);

        __syncthreads();
        cur ^= 1;
    }
#undef QKV_STAGE

    if (which == 2) {
#pragma unroll
        for (int i = 0; i < 4; ++i)
#pragma unroll
            for (int j = 0; j < 4; ++j) {
                const int n = n0 + wn + (j << 4) + l15;
                const int h = n >> 6, hd = n & 63;
                const int mb = m0 + wm + (i << 4) + (quad << 2);
                const int b = mb >> 11, t = mb & 2047;
                ushort4 pk;
                pk.x = f2bf(acc[i][j][0]); pk.y = f2bf(acc[i][j][1]);
                pk.z = f2bf(acc[i][j][2]); pk.w = f2bf(acc[i][j][3]);
                *(ushort4*)&vo[((((size_t)(b * NH + h) << 6) + hd) << 11) + t] = pk;
            }
    } else {
        unsigned short* outp = (which == 0) ? qo : ko;
        const float sc = (which == 1) ? 0.125f : 1.0f;
#pragma unroll
        for (int p = 0; p < 2; ++p) {
            __syncthreads();
            if ((wid >> 1) == p) {
#pragma unroll
                for (int i = 0; i < 4; ++i)
#pragma unroll
                    for (int j = 0; j < 4; ++j)
#pragma unroll
                        for (int r = 0; r < 4; ++r) {
                            const int row = (i << 4) + (quad << 2) + r;
                            SMEM[row * 136 + wn + (j << 4) + l15] = f2bf(acc[i][j][r] * sc);
                        }
            }
            __syncthreads();
            const int rr = tid >> 2;
            const int cg = (tid & 3) << 5;
            const int m = m0 + (p << 6) + rr;
            const int b = m >> 11, t = m & 2047;
#pragma unroll
            for (int k2 = 0; k2 < 4; ++k2) {
                const int n = n0 + cg + (k2 << 3);
                const int h = n >> 6, hd = n & 63;
                const uint4 val = *(const uint4*)&SMEM[rr * 136 + cg + (k2 << 3)];
                *(uint4*)&outp[(((size_t)(b * NH + h) * TT + t) << 6) + hd] = val;
            }
        }
    }
}

// ============================================================================
// Flash attention, bf16 MFMA, S^T formulation.
// R7a: XCD-locality swizzle — lin = bx + 16*by; bh = lin&31, pair = lin>>5.
//   All 16 blocks of one bh share lin%8 -> same XCD (round-robin dispatch)
//   -> that bh's 512 KB K/V stays in one L2 slice.  Heuristic only.
// R7b: single-barrier double-buffered K/V staging (R6 qkv pattern): global
//   uint4 loads for tile jt+1 issued at iteration top, compute jt from buf A,
//   ds_write B, one barrier.  LDS 45 KB (Qs + 2xKs + 2xVts, stride 72).
// ============================================================================
__global__ __launch_bounds__(256) void attn_mfma(
    const unsigned short* __restrict__ q, const unsigned short* __restrict__ k,
    const unsigned short* __restrict__ vt, unsigned short* __restrict__ ctx)
{
    __shared__ unsigned short Qs[64][72];
    __shared__ unsigned short Ks[2][64][72];
    __shared__ unsigned short Vts[2][64][72];

    const int tid = threadIdx.x;
    const int lane = tid & 63;
    const int wid = tid >> 6;
    const int l15 = lane & 15, quad = lane >> 4;

    // XCD swizzle: same-bh blocks -> same lin%8 -> same XCD's L2
    const int lin = (int)blockIdx.x + ((int)blockIdx.y << 4);
    const int bh = lin & 31;
    const int pair = lin >> 5;                // 0..15

    const unsigned short* qb = q + (size_t)bh * TT * HDD;
    const unsigned short* kb = k + (size_t)bh * TT * HDD;
    const unsigned short* vb = vt + (size_t)bh * HDD * TT;   // (HD, T)
    unsigned short* cb = ctx + (size_t)bh * TT * HDD;

    const int cr = tid >> 3;            // staging row 0..31 (x2 rounds)
    const int cc = (tid & 7) << 3;      // staging col (ushort), 16B chunks

    for (int half = 0; half < 2; ++half) {
        const int qt = half ? (31 - pair) : pair;
        const int q0 = qt << 6;
        const int qrow = q0 + (wid << 4) + l15;   // this lane's q-row

        __syncthreads();                // prev-half LDS reads done
#pragma unroll
        for (int u = 0; u < 2; ++u) {
            const int r = cr + (u << 5);
            *(uint4*)&Qs[r][cc] = *(const uint4*)&qb[(size_t)(q0 + r) * HDD + cc];
        }
        // K/V tile 0 -> regs -> buf0
        {
            uint4 k0r = *(const uint4*)&kb[(size_t)cr * HDD + cc];
            uint4 k1r = *(const uint4*)&kb[(size_t)(cr + 32) * HDD + cc];
            uint4 v0r = *(const uint4*)&vb[((size_t)cr << 11) + cc];
            uint4 v1r = *(const uint4*)&vb[((size_t)(cr + 32) << 11) + cc];
            *(uint4*)&Ks[0][cr][cc] = k0r;
            *(uint4*)&Ks[0][cr + 32][cc] = k1r;
            *(uint4*)&Vts[0][cr][cc] = v0r;
            *(uint4*)&Vts[0][cr + 32][cc] = v1r;
        }
        __syncthreads();

        // Q B-frags, wave-resident for the k-loop
        v8s qf[2];
#pragma unroll
        for (int c = 0; c < 2; ++c)
            qf[c] = *(const v8s*)&Qs[(wid << 4) + l15][(c << 5) + (quad << 3)];

        float m_i = -INFINITY, l_i = 0.f;
        f32x4 o[4] = {};                // O^T: d = m*16 + quad*4 + r, col q=l15

        for (int jt = 0; jt <= qt; ++jt) {
            const int cur = jt & 1;

            // issue global loads for tile jt+1 (land during compute below)
            uint4 k0r, k1r, v0r, v1r;
            const bool pre = (jt < qt);
            if (pre) {
                const int kn = (jt + 1) << 6;
                k0r = *(const uint4*)&kb[(size_t)(kn + cr) * HDD + cc];
                k1r = *(const uint4*)&kb[(size_t)(kn + cr + 32) * HDD + cc];
                v0r = *(const uint4*)&vb[((size_t)cr << 11) + kn + cc];
                v1r = *(const uint4*)&vb[((size_t)(cr + 32) << 11) + kn + cc];
            }

            const int k0 = jt << 6;

            // S^T = K . Q^T : St[k = m*16+quad*4+r][q = l15]  (K pre-scaled)
            f32x4 s[4] = {};
#pragma unroll
            for (int m = 0; m < 4; ++m) {
                const v8s kf0 = *(const v8s*)&Ks[cur][(m << 4) + l15][quad << 3];
                const v8s kf1 = *(const v8s*)&Ks[cur][(m << 4) + l15][32 + (quad << 3)];
                s[m] = __builtin_amdgcn_mfma_f32_16x16x32_bf16(kf0, qf[0], s[m], 0, 0, 0);
                s[m] = __builtin_amdgcn_mfma_f32_16x16x32_bf16(kf1, qf[1], s[m], 0, 0, 0);
            }

            if (jt == qt) {             // causal mask, diagonal tile only
#pragma unroll
                for (int m = 0; m < 4; ++m) {
                    const int kc = k0 + (m << 4) + (quad << 2);
#pragma unroll
                    for (int r = 0; r < 4; ++r)
                        if (kc + r > qrow) s[m][r] = -INFINITY;
                }
            }

            // online softmax: one q-row per lane (16 in-reg values, 2 shfl)
            float mx = fmaxf(fmaxf(s[0][0], s[0][1]), fmaxf(s[0][2], s[0][3]));
            mx = fmaxf(mx, fmaxf(fmaxf(s[1][0], s[1][1]), fmaxf(s[1][2], s[1][3])));
            mx = fmaxf(mx, fmaxf(fmaxf(s[2][0], s[2][1]), fmaxf(s[2][2], s[2][3])));
            mx = fmaxf(mx, fmaxf(fmaxf(s[3][0], s[3][1]), fmaxf(s[3][2], s[3][3])));
            mx = fmaxf(mx, __shfl_xor(mx, 16));
            mx = fmaxf(mx, __shfl_xor(mx, 32));
            const float m_new = fmaxf(m_i, mx);
            const float alpha = __expf(m_i - m_new);
            m_i = m_new;

            float sum = 0.f;
            v4s pf[4];
#pragma unroll
            for (int m = 0; m < 4; ++m) {
                v4s t;
#pragma unroll
                for (int r = 0; r < 4; ++r) {
                    const float pv = __expf(s[m][r] - m_new);
                    sum += pv;
                    t[r] = (short)f2bf(pv);
                }
                pf[m] = t;
            }
            sum += __shfl_xor(sum, 16);
            sum += __shfl_xor(sum, 32);
            l_i = l_i * alpha + sum;

#pragma unroll
            for (int m = 0; m < 4; ++m)
#pragma unroll
                for (int r = 0; r < 4; ++r)
                    o[m][r] *= alpha;

            // O^T += Vt . P^T   (A = Vt 16x16 chunk, B = P^T chunk from regs)
#pragma unroll
            for (int m = 0; m < 4; ++m)
#pragma unroll
                for (int c = 0; c < 4; ++c) {
                    const v4s vf = *(const v4s*)&Vts[cur][(m << 4) + l15][(c << 4) + (quad << 2)];
                    o[m] = mfma16x16x16bf16(vf, pf[c], o[m]);
                }

            // publish tile jt+1 into the other buffer (safe: its readers
            // finished before the barrier at the end of iteration jt-1)
            if (pre) {
                const int nxt = cur ^ 1;
                *(uint4*)&Ks[nxt][cr][cc] = k0r;
                *(uint4*)&Ks[nxt][cr + 32][cc] = k1r;
                *(uint4*)&Vts[nxt][cr][cc] = v0r;
                *(uint4*)&Vts[nxt][cr + 32][cc] = v1r;
            }
            __syncthreads();
        }

        // normalize + store: ctx[q][d], d = m*16 + quad*4 + r (8B stores)
        const float linv = 1.f / l_i;
#pragma unroll
        for (int m = 0; m < 4; ++m) {
            ushort4 st;
            st.x = f2bf(o[m][0] * linv); st.y = f2bf(o[m][1] * linv);
            st.z = f2bf(o[m][2] * linv); st.w = f2bf(o[m][3] * linv);
            *(ushort4*)&cb[((size_t)qrow << 6) + (m << 4) + (quad << 2)] = st;
        }
    }
}

// ============================================================================
// Output projection (unchanged from R6: double-buffered K-loop).
// ============================================================================
__global__ __launch_bounds__(256) void oproj_mfma(
    const unsigned short* __restrict__ c, const unsigned short* __restrict__ wo,
    const float* __restrict__ bo, float* __restrict__ out)
{
    __shared__ unsigned short SMEM[16384];    // 32 KB

    const int tid = threadIdx.x;
    const int lane = tid & 63;
    const int wid = tid >> 6;
    const int l15 = lane & 15, quad = lane >> 4;

    const int m0 = blockIdx.x << 7;
    const int n0 = blockIdx.y << 7;
    const int wm = (wid >> 1) << 6, wn = (wid & 1) << 6;

    const int f0 = (wid << 11) + (lane << 4);
    const int row0 = f0 >> 6, cs0 = (f0 & 63) >> 1;
    const int f1 = f0 + 1024;
    const int row1 = f1 >> 6, cs1 = (f1 & 63) >> 1;

    char* const smem = (char*)SMEM;

#define OP_STAGE(k0, buf)                                                      \
    do {                                                                       \
        gload_lds16(&c[(size_t)(m0 + row0) * DD + (k0) + cs0],                 \
                    smem + (buf) * 8192 + f0);                                 \
        gload_lds16(&c[(size_t)(m0 + row1) * DD + (k0) + cs1],                 \
                    smem + (buf) * 8192 + f1);                                 \
        gload_lds16(&wo[(size_t)(n0 + row0) * DD + (k0) + cs0],                \
                    smem + 16384 + (buf) * 8192 + f0);                         \
        gload_lds16(&wo[(size_t)(n0 + row1) * DD + (k0) + cs1],                \
                    smem + 16384 + (buf) * 8192 + f1);                         \
    } while (0)

    f32x4 acc[4][4] = {};

    OP_STAGE(0, 0);
    __syncthreads();

    int cur = 0;
    for (int k0 = 0; k0 < DD; k0 += 32) {
        if (k0 + 32 < DD) OP_STAGE(k0 + 32, cur ^ 1);

        const char* Ab = smem + cur * 8192;
        const char* Bb = smem + 16384 + cur * 8192;
        v8s af[4], bf[4];
#pragma unroll
        for (int i = 0; i < 4; ++i)
            af[i] = *(const v8s*)(Ab + (wm + (i << 4) + l15) * 64 + (quad << 4));
#pragma unroll
        for (int j = 0; j < 4; ++j)
            bf[j] = *(const v8s*)(Bb + (wn + (j << 4) + l15) * 64 + (quad << 4));
#pragma unroll
        for (int i = 0; i < 4; ++i)
#pragma unroll
            for (int j = 0; j < 4; ++j)
                acc[i][j] = __builtin_amdgcn_mfma_f32_16x16x32_bf16(af[i], bf[j], acc[i][j], 0, 0, 0);

        __syncthreads();
        cur ^= 1;
    }
#undef OP_STAGE

#pragma unroll
    for (int j = 0; j < 4; ++j) {
        const int n = n0 + wn + (j << 4) + l15;
        const float bias = bo[n];
#pragma unroll
        for (int i = 0; i < 4; ++i) {
            const int mb = m0 + wm + (i << 4) + (quad << 2);
#pragma unroll
            for (int r = 0; r < 4; ++r)
                out[(size_t)(mb + r) * DD + n] = acc[i][j][r] + bias;
        }
    }
}

extern "C" void kernel_launch(void* const* d_in, const int* in_sizes, int n_in,
                              void* d_out, int out_size, void* d_ws, size_t ws_size,
                              hipStream_t stream) {
    const float* x  = (const float*)d_in[0];
    const float* Wq = (const float*)d_in[1];
    const float* Wk = (const float*)d_in[2];
    const float* Wv = (const float*)d_in[3];
    const float* Wo = (const float*)d_in[4];
    const float* bo = (const float*)d_in[5];
    float* out = (float*)d_out;

    const size_t NX = (size_t)BB * TT * DD;
    const size_t NW = (size_t)DD * DD;

    unsigned short* xb  = (unsigned short*)d_ws;
    unsigned short* wqb = xb + NX;
    unsigned short* wkb = wqb + NW;
    unsigned short* wvb = wkb + NW;
    unsigned short* wob = wvb + NW;
    unsigned short* qb  = wob + NW;
    unsigned short* kb  = qb + NX;
    unsigned short* vtb = kb + NX;
    unsigned short* cbuf = vtb + NX;

    cast5_kernel<<<dim3(4096, 5), 256, 0, stream>>>(x, Wq, Wk, Wv, Wo,
                                                    xb, wqb, wkb, wvb, wob);
    qkv_mfma<<<dim3(32, 24), 256, 0, stream>>>(xb, wqb, wkb, wvb, qb, kb, vtb);
    attn_mfma<<<dim3(16, 32), 256, 0, stream>>>(qb, kb, vtb, cbuf);
    oproj_mfma<<<dim3(32, 8), 256, 0, stream>>>(cbuf, wob, bo, out);
}